// Round 2
// baseline (245.740 us; speedup 1.0000x reference)
//
#include <hip/hip_runtime.h>
#include <math.h>

#define BATCH 16
#define CH 256
#define HW 56
#define NPIX (HW*HW)          // 3136

// padded x_fuse plane layout: 56 rows x 68 cols; image col j at col j+4.
// cols 0..3 and 60..67 are zero pads. OOB rows handled via shared zero row.
#define FSTRIDE 68
#define FPLANE (56*FSTRIDE)   // 3808

// ---------------- Kernel 1: one thread per pool cell (8x8), no LDS, no barriers ----
// Also stores the fused plane (padded) to global for k3, and writes side pads + zrow.
#define K1_LOAD_ROW(r, dst) do {                                                 \
    const int   rr_  = (r);                                                      \
    const bool  rok_ = ((unsigned)rr_ < 56u);                                    \
    const float* rp_ = plane + (rok_ ? rr_ : 0) * 56;                            \
    float4 a_ = *(const float4*)(rp_ + col0);                                    \
    float4 b_ = *(const float4*)(rp_ + cbase + 4);                               \
    float4 c_ = *(const float4*)(rp_ + cbase + 8);                               \
    float4 d_ = *(const float4*)(rp_ + col3);                                    \
    const bool l_ = rok_ && (cx > 0);                                            \
    const bool r_ = rok_ && (cx < 6);                                            \
    (dst)[0]=l_?a_.x:0.f;  (dst)[1]=l_?a_.y:0.f;  (dst)[2]=l_?a_.z:0.f;  (dst)[3]=l_?a_.w:0.f;   \
    (dst)[4]=rok_?b_.x:0.f;(dst)[5]=rok_?b_.y:0.f;(dst)[6]=rok_?b_.z:0.f;(dst)[7]=rok_?b_.w:0.f; \
    (dst)[8]=rok_?c_.x:0.f;(dst)[9]=rok_?c_.y:0.f;(dst)[10]=rok_?c_.z:0.f;(dst)[11]=rok_?c_.w:0.f;\
    (dst)[12]=r_?d_.x:0.f; (dst)[13]=r_?d_.y:0.f; (dst)[14]=r_?d_.z:0.f; (dst)[15]=r_?d_.w:0.f; \
} while (0)

__global__ __launch_bounds__(256) void k1_cell(
    const float* __restrict__ x1,
    const float* __restrict__ dw1w, const float* __restrict__ g1, const float* __restrict__ b1,
    const float* __restrict__ m1, const float* __restrict__ v1,
    const float* __restrict__ dw2w, const float* __restrict__ g2, const float* __restrict__ b2,
    const float* __restrict__ m2, const float* __restrict__ v2,
    float* __restrict__ pooled,   // [B*C*49]
    float* __restrict__ xf,       // [B*C][FPLANE] padded fused planes
    float* __restrict__ zrow)     // 80 floats, zeroed
{
    const int g    = blockIdx.x * 256 + threadIdx.x;   // 0..200703
    const int bc   = g / 49;
    const int cell = g - bc * 49;
    const int c    = bc & 255;
    const int cy   = cell / 7, cx = cell - cy * 7;
    const float* plane = x1 + (size_t)bc * NPIX;
    float* fp = xf + (size_t)bc * FPLANE;

    const float4 z4 = make_float4(0.f, 0.f, 0.f, 0.f);
    if (g < 20) ((float4*)zrow)[g] = z4;

    float w1[9], w2[9];
    #pragma unroll
    for (int k = 0; k < 9; k++) { w1[k] = dw1w[c*9+k]; w2[k] = dw2w[c*9+k]; }
    const float sc1 = g1[c] * rsqrtf(v1[c] + 1e-5f);
    const float be1 = b1[c] - m1[c] * sc1;
    const float sc2 = g2[c] * rsqrtf(v2[c] + 1e-5f);
    const float be2 = b2[c] - m2[c] * sc2;

    const int rbase = 8*cy - 1;
    const int cbase = 8*cx - 4;                 // rows[s][m] <-> image col cbase+m
    const int col0  = (cx > 0) ? cbase      : 0;
    const int col3  = (cx < 6) ? cbase + 12 : 0;

    float rows[3][16];
    K1_LOAD_ROW(rbase + 0, rows[0]);
    K1_LOAD_ROW(rbase + 1, rows[1]);

    float sum = 0.f;
    #pragma unroll
    for (int yy = 0; yy < 8; yy++) {            // output row 8cy+yy
        K1_LOAD_ROW(rbase + yy + 2, rows[(yy + 2) % 3]);
        float y1[8], y2[8];
        #pragma unroll
        for (int e = 0; e < 8; e++) { y1[e] = 0.f; y2[e] = 0.f; }
        #pragma unroll
        for (int ky = 0; ky < 3; ky++) {
            const float* rr = rows[(yy + ky) % 3];   // image row rbase+yy+ky
            #pragma unroll
            for (int e = 0; e < 8; e++)
                #pragma unroll
                for (int kx = 0; kx < 3; kx++) {
                    float xv = rr[3 + e + kx];       // image col 8cx+e+kx-1
                    y1[e] += xv * w1[ky*3+kx];
                    y2[e] += xv * w2[ky*3+kx];
                }
        }
        float f[8];
        #pragma unroll
        for (int e = 0; e < 8; e++) {
            float a = fminf(fmaxf(y1[e]*sc1 + be1, 0.f), 6.f);
            f[e] = a * (y2[e]*sc2 + be2);
            sum += f[e];
        }
        // store fused row (image row 8cy+yy, cols 8cx..8cx+7) into padded plane
        float* orow = fp + (8*cy + yy) * FSTRIDE;
        float4 q0; q0.x=f[0]; q0.y=f[1]; q0.z=f[2]; q0.w=f[3];
        float4 q1; q1.x=f[4]; q1.y=f[5]; q1.z=f[6]; q1.w=f[7];
        *(float4*)(orow + 4 + 8*cx)     = q0;
        *(float4*)(orow + 4 + 8*cx + 4) = q1;
        if (cx == 0) *(float4*)(orow + 0)  = z4;                 // left pad
        if (cx == 6) { *(float4*)(orow + 60) = z4; *(float4*)(orow + 64) = z4; }  // right pad
    }
    pooled[(size_t)bc * 49 + cell] = sum * (1.f/64.f);
}

// ---------------- Kernel 2 (fused): per (b, p) block: proj1 -> GELU -> proj2 ->
// softmax over G -> dynamic weight/bias. grid = 16*50 = 800 blocks x 256 threads.
// p = 49 is the channel-mean column (dynamic bias path).
__global__ __launch_bounds__(256) void k2_fused(
    const float* __restrict__ pooled,
    const float* __restrict__ pw1, const float* __restrict__ pb1,
    const float* __restrict__ pw2, const float* __restrict__ pb2,
    const float* __restrict__ weight1, const float* __restrict__ bias1,
    float* __restrict__ w_dyn,    // [B*C][64] (stride 64, cols 0..48 valid)
    float* __restrict__ b_dyn)    // [B*C]
{
    const int blk = blockIdx.x;
    const int b = blk / 50, p = blk - b * 50;
    const int t = threadIdx.x;

    __shared__ __attribute__((aligned(16))) float xs[268];  // x[c] at c + 4*(c>>6)
    __shared__ __attribute__((aligned(16))) float hs[64];

    {   // stage input column (or mean column for p==49)
        const float* pp = pooled + ((size_t)b * 256 + t) * 49;
        float v;
        if (p < 49) {
            v = pp[p];
        } else {
            float s = 0.f;
            #pragma unroll
            for (int q = 0; q < 49; q++) s += pp[q];
            v = s * (1.f/49.f);
        }
        xs[t + 4*(t>>6)] = v;
    }
    __syncthreads();

    {   // proj1: 64 outputs, 4 lanes each (len-64 partials), shfl reduce, GELU
        const int o = t >> 2, part = t & 3;
        const float4* w4 = (const float4*)(pw1 + o*256 + part*64);
        const float4* x4 = (const float4*)(xs + part*68);   // 68 % 4 == 0, conflict-free
        float acc = 0.f;
        #pragma unroll
        for (int i = 0; i < 16; i++) {
            float4 w = w4[i];
            float4 x = x4[i];
            acc += w.x*x.x + w.y*x.y + w.z*x.z + w.w*x.w;
        }
        acc += __shfl_xor(acc, 1);
        acc += __shfl_xor(acc, 2);
        if (part == 0) {
            float zv = acc + pb1[o];
            hs[o] = 0.5f * zv * (1.f + erff(zv * 0.70710678118654752f));
        }
    }
    __syncthreads();

    {   // proj2 for this thread's channel c = t, all 4 groups; in-register softmax
        float s[4];
        #pragma unroll
        for (int gg = 0; gg < 4; gg++) {
            const int o2 = (gg << 8) + t;
            const float4* w4 = (const float4*)(pw2 + (size_t)o2 * 64);
            float acc = pb2[o2];
            #pragma unroll
            for (int j = 0; j < 16; j++) {
                float4 w = w4[j];
                const float4 h = *(const float4*)(hs + 4*j);   // broadcast
                acc += w.x*h.x + w.y*h.y + w.z*h.z + w.w*h.w;
            }
            s[gg] = acc;
        }
        float mx = fmaxf(fmaxf(s[0], s[1]), fmaxf(s[2], s[3]));
        float e0 = expf(s[0]-mx), e1 = expf(s[1]-mx), e2 = expf(s[2]-mx), e3 = expf(s[3]-mx);
        float inv = 1.f / (e0+e1+e2+e3);
        e0 *= inv; e1 *= inv; e2 *= inv; e3 *= inv;
        if (p < 49) {
            float wv = e0*weight1[(0*256+t)*49+p] + e1*weight1[(1*256+t)*49+p]
                     + e2*weight1[(2*256+t)*49+p] + e3*weight1[(3*256+t)*49+p];
            w_dyn[((size_t)b*256 + t)*64 + p] = wv;
        } else {
            b_dyn[b*256 + t] = e0*bias1[t] + e1*bias1[256+t] + e2*bias1[512+t] + e3*bias1[768+t];
        }
    }
}

// ---------------- Kernel 3: direct dynamic 7x7 conv from padded global x_fuse ----
// One thread per 4x4 output tile. grid = 3136 x 256 = 4096 planes * 196 tiles,
// zero idle lanes, no LDS, no barriers. Boundary cols via plane padding,
// boundary rows via zrow pointer redirect (no selects in the inner loop).
__global__ __launch_bounds__(256) void k3_direct(
    const float* __restrict__ xf, const float* __restrict__ zrow,
    const float* __restrict__ w_dyn, const float* __restrict__ b_dyn,
    float* __restrict__ out)
{
    const int g  = blockIdx.x * 256 + threadIdx.x;   // 0..802815
    const int bc = g / 196;
    const int tl = g - bc * 196;
    const int ty = tl / 14, tx = tl - ty * 14;
    const int oy = ty * 4, ox = tx * 4;
    const float* fp = xf + (size_t)bc * FPLANE;

    float wk[52];
    {
        const float4* w4 = (const float4*)(w_dyn + (size_t)bc * 64);
        #pragma unroll
        for (int i = 0; i < 13; i++) {
            float4 v = w4[i];
            wk[4*i]=v.x; wk[4*i+1]=v.y; wk[4*i+2]=v.z; wk[4*i+3]=v.w;
        }
    }
    const float bias = b_dyn[bc];

    float acc[4][4];
    #pragma unroll
    for (int a = 0; a < 4; a++)
        #pragma unroll
        for (int bb = 0; bb < 4; bb++) acc[a][bb] = bias;

    #pragma unroll
    for (int iy = 0; iy < 10; iy++) {
        const int r = oy - 3 + iy;
        const float* rp = ((unsigned)r < 56u) ? (fp + r * FSTRIDE) : zrow;
        float4 A = *(const float4*)(rp + ox);        // padded cols ox..ox+15
        float4 B = *(const float4*)(rp + ox + 4);    //  = image cols ox-4..ox+11
        float4 C = *(const float4*)(rp + ox + 8);
        float4 D = *(const float4*)(rp + ox + 12);
        float row[16];
        row[0]=A.x; row[1]=A.y; row[2]=A.z; row[3]=A.w;
        row[4]=B.x; row[5]=B.y; row[6]=B.z; row[7]=B.w;
        row[8]=C.x; row[9]=C.y; row[10]=C.z; row[11]=C.w;
        row[12]=D.x; row[13]=D.y; row[14]=D.z; row[15]=D.w;
        #pragma unroll
        for (int tyy = 0; tyy < 4; tyy++) {
            const int ky = iy - tyy;
            if (ky >= 0 && ky < 7) {
                #pragma unroll
                for (int txx = 0; txx < 4; txx++)
                    #pragma unroll
                    for (int kx = 0; kx < 7; kx++)
                        acc[tyy][txx] += row[1 + txx + kx] * wk[ky*7 + kx];
            }
        }
    }

    float* op = out + (size_t)bc * NPIX;
    #pragma unroll
    for (int tyy = 0; tyy < 4; tyy++) {
        float4 r4; r4.x = acc[tyy][0]; r4.y = acc[tyy][1]; r4.z = acc[tyy][2]; r4.w = acc[tyy][3];
        *(float4*)(op + (oy+tyy)*56 + ox) = r4;
    }
}

extern "C" void kernel_launch(void* const* d_in, const int* in_sizes, int n_in,
                              void* d_out, int out_size, void* d_ws, size_t ws_size,
                              hipStream_t stream) {
    const float* x1    = (const float*)d_in[0];
    const float* dw1w  = (const float*)d_in[1];
    const float* dw1g  = (const float*)d_in[2];
    const float* dw1b  = (const float*)d_in[3];
    const float* dw1m  = (const float*)d_in[4];
    const float* dw1v  = (const float*)d_in[5];
    const float* dw2w  = (const float*)d_in[6];
    const float* dw2g  = (const float*)d_in[7];
    const float* dw2b  = (const float*)d_in[8];
    const float* dw2m  = (const float*)d_in[9];
    const float* dw2v  = (const float*)d_in[10];
    const float* weight1 = (const float*)d_in[11];
    const float* bias1   = (const float*)d_in[12];
    const float* pw1     = (const float*)d_in[13];
    const float* pb1     = (const float*)d_in[14];
    const float* pw2     = (const float*)d_in[15];
    const float* pb2     = (const float*)d_in[16];

    float* out = (float*)d_out;
    float* ws  = (float*)d_ws;
    // ws layout (floats):
    float* pooled = ws;                    // 200,704
    float* w_dyn  = ws + 200704;           // 4096*64 = 262,144
    float* b_dyn  = ws + 462848;           // 4,096
    float* zrow   = ws + 466944;           // 80
    float* xf     = ws + 467024;           // 4096*3808 = 15,597,568 (~64 MB total)

    k1_cell<<<784, 256, 0, stream>>>(x1, dw1w, dw1g, dw1b, dw1m, dw1v,
                                     dw2w, dw2g, dw2b, dw2m, dw2v,
                                     pooled, xf, zrow);
    k2_fused<<<800, 256, 0, stream>>>(pooled, pw1, pb1, pw2, pb2,
                                      weight1, bias1, w_dyn, b_dyn);
    k3_direct<<<3136, 256, 0, stream>>>(xf, zrow, w_dyn, b_dyn, out);
}

// Round 3
// 191.868 us; speedup vs baseline: 1.2808x; 1.2808x over previous
//
#include <hip/hip_runtime.h>
#include <math.h>

#define BATCH 16
#define CH 256
#define HW 56
#define NPIX (HW*HW)          // 3136

// ---- shared device helper: compute 4x4 tile of x_fuse = relu6(bn1(dw1(x))) * bn2(dw2(x))
// via direct global reads of the (L1/L3-resident) x1 plane. Tile at rows 4ty..4ty+3,
// cols 4tx..4tx+3 (ty,tx in 0..13).
__device__ __forceinline__ void fuse_tile(
    const float* __restrict__ plane, int ty, int tx,
    const float w1[9], const float w2[9],
    float sc1, float be1, float sc2, float be2,
    float res[4][4])
{
    const int oy = 4 * ty;
    float y1a[4][4], y2a[4][4];
    #pragma unroll
    for (int a = 0; a < 4; a++)
        #pragma unroll
        for (int e = 0; e < 4; e++) { y1a[a][e] = 0.f; y2a[a][e] = 0.f; }

    #pragma unroll
    for (int iy = 0; iy < 6; iy++) {         // input rows oy-1 .. oy+4
        const int r    = oy - 1 + iy;
        const bool rok = (r >= 0) && (r < 56);
        const int rc   = rok ? r : 0;
        float rb[12];                         // rb[m] = image col 4tx-4+m
        #pragma unroll
        for (int k = 0; k < 3; k++) {
            const int cx  = tx - 1 + k;
            const bool cv = (cx >= 0) && (cx < 14);
            const int cc2 = cv ? cx : 0;
            const bool ok = rok && cv;
            float4 v = *(const float4*)(plane + rc*56 + 4*cc2);  // always in-bounds
            rb[4*k+0] = ok ? v.x : 0.f;
            rb[4*k+1] = ok ? v.y : 0.f;
            rb[4*k+2] = ok ? v.z : 0.f;
            rb[4*k+3] = ok ? v.w : 0.f;
        }
        #pragma unroll
        for (int tyy = 0; tyy < 4; tyy++) {
            const int ky = iy - tyy;          // tap row, needs 0..2
            if (ky >= 0 && ky < 3) {
                #pragma unroll
                for (int e = 0; e < 4; e++)
                    #pragma unroll
                    for (int dj = 0; dj < 3; dj++) {
                        float xv = rb[3 + e + dj];   // image col 4tx+e+dj-1
                        y1a[tyy][e] += xv * w1[ky*3+dj];
                        y2a[tyy][e] += xv * w2[ky*3+dj];
                    }
            }
        }
    }
    #pragma unroll
    for (int tyy = 0; tyy < 4; tyy++)
        #pragma unroll
        for (int e = 0; e < 4; e++) {
            float y1 = y1a[tyy][e] * sc1 + be1;
            float y2 = y2a[tyy][e] * sc2 + be2;
            float a = fminf(fmaxf(y1, 0.f), 6.f);
            res[tyy][e] = a * y2;
        }
}

// ---------------- Kernel 1: fuse (no store) -> pooled block means only ----
// Round-0 structure (4096 blocks). Store transposed: pooled[b][cell][c].
__global__ __launch_bounds__(256) void k1_pool(
    const float* __restrict__ x1,
    const float* __restrict__ dw1w, const float* __restrict__ g1, const float* __restrict__ b1,
    const float* __restrict__ m1, const float* __restrict__ v1,
    const float* __restrict__ dw2w, const float* __restrict__ g2, const float* __restrict__ b2,
    const float* __restrict__ m2, const float* __restrict__ v2,
    float* __restrict__ pooled)  // ws: [B][50][C]  (rows 0..48 written here)
{
    const int bc = blockIdx.x;        // b*256 + c
    const int c  = bc & 255;
    const int b  = bc >> 8;
    const int t  = threadIdx.x;

    __shared__ float part[196];

    float w1[9], w2[9];
    #pragma unroll
    for (int k = 0; k < 9; k++) { w1[k] = dw1w[c*9+k]; w2[k] = dw2w[c*9+k]; }
    const float sc1 = g1[c] * rsqrtf(v1[c] + 1e-5f);
    const float be1 = b1[c] - m1[c] * sc1;
    const float sc2 = g2[c] * rsqrtf(v2[c] + 1e-5f);
    const float be2 = b2[c] - m2[c] * sc2;

    if (t < 196) {
        const int ty = t / 14, tx = t - ty * 14;
        float res[4][4];
        fuse_tile(x1 + (size_t)bc * NPIX, ty, tx, w1, w2, sc1, be1, sc2, be2, res);
        float s = 0.f;
        #pragma unroll
        for (int a = 0; a < 4; a++)
            #pragma unroll
            for (int e = 0; e < 4; e++) s += res[a][e];
        part[t] = s;   // tile (ty,tx) lies wholly in pool cell (ty>>1, tx>>1)
    }
    __syncthreads();
    if (t < 49) {
        int ph = t / 7, pw = t - ph * 7;
        float s = part[(2*ph  )*14 + 2*pw] + part[(2*ph  )*14 + 2*pw + 1]
                + part[(2*ph+1)*14 + 2*pw] + part[(2*ph+1)*14 + 2*pw + 1];
        pooled[((size_t)(b * 50 + t)) * 256 + c] = s * (1.f/64.f);
    }
}

// ---------------- Kernel 2a': per (b,p) block: coalesced stage -> proj1 -> GELU ----
// grid = 16*50 = 800 blocks x 256 threads. p==49 is the channel-mean column.
__global__ __launch_bounds__(256) void k2a(
    const float* __restrict__ pooled,  // [B][50][C], rows 0..48 valid
    const float* __restrict__ pw1, const float* __restrict__ pb1,
    float* __restrict__ h)             // [B][50][64]
{
    const int blk = blockIdx.x;
    const int b = blk / 50, p = blk - b * 50;
    const int t = threadIdx.x;

    __shared__ __attribute__((aligned(16))) float xs[272];  // x[c] at c + 4*(c>>6)

    const float* base = pooled + (size_t)b * 50 * 256;
    float v;
    if (p < 49) {
        v = base[p * 256 + t];                       // coalesced
    } else {
        float s = 0.f;
        #pragma unroll 7
        for (int q = 0; q < 49; q++) s += base[q * 256 + t];   // coalesced rows
        v = s * (1.f/49.f);
    }
    xs[t + 4*(t>>6)] = v;
    __syncthreads();

    // proj1: 64 outputs, 4 lanes each (len-64 partials), shfl reduce, GELU
    const int o = t >> 2, part = t & 3;
    const float4* w4 = (const float4*)(pw1 + o*256 + part*64);
    const float4* x4 = (const float4*)(xs + part*68);   // LDS broadcast, conflict-free
    float acc = 0.f;
    #pragma unroll
    for (int i = 0; i < 16; i++) {
        float4 w = w4[i];
        float4 x = x4[i];
        acc += w.x*x.x + w.y*x.y + w.z*x.z + w.w*x.w;
    }
    acc += __shfl_xor(acc, 1);
    acc += __shfl_xor(acc, 2);
    if (part == 0) {
        float zv = acc + pb1[o];
        h[((size_t)b * 50 + p) * 64 + o] = 0.5f * zv * (1.f + erff(zv * 0.70710678118654752f));
    }
}

// ---------------- Kernel 2b': proj2 + softmax over G + dynamic w/b ------------
// grid = (16 b, 16 c-chunks) x 256 threads. All operands staged in LDS:
// ht[k][p] (conflict-free x reads), wg[cl][k][g] (float4 broadcast reads).
__global__ __launch_bounds__(256) void k2b(
    const float* __restrict__ h, const float* __restrict__ pw2, const float* __restrict__ pb2,
    const float* __restrict__ weight1, const float* __restrict__ bias1,
    float* __restrict__ w_dyn,   // [B*C][49]  (k3-native layout)
    float* __restrict__ b_dyn)   // [B*C]
{
    const int b   = blockIdx.x;
    const int cch = blockIdx.y;       // 0..15, 16 channels each
    const int t   = threadIdx.x;
    const int c_base = cch * 16;

    __shared__ float ht[64*52];                                   // 13.3 KB [k][p]
    __shared__ __attribute__((aligned(16))) float wg[16*64*4];    // 16 KB [cl][k][g]

    // stage h transposed: global [p][k] -> LDS [k][p]
    const float* hp = h + (size_t)b * 50 * 64;
    for (int idx = t; idx < 800; idx += 256) {
        const int p = idx >> 4, k4 = idx & 15;
        float4 v = ((const float4*)(hp + p * 64))[k4];
        ht[(4*k4+0)*52 + p] = v.x;
        ht[(4*k4+1)*52 + p] = v.y;
        ht[(4*k4+2)*52 + p] = v.z;
        ht[(4*k4+3)*52 + p] = v.w;
    }
    // stage pw2 rows for the 64 outputs {g*256 + c_base + cl} as [cl][k][g]
    for (int idx = t; idx < 1024; idx += 256) {
        const int r = idx >> 4, k4 = idx & 15;    // r = g*16+cl
        const int g = r >> 4, cl = r & 15;
        const int o2 = (g << 8) + c_base + cl;
        float4 v = ((const float4*)(pw2 + (size_t)o2 * 64))[k4];
        wg[((cl*64) + 4*k4+0)*4 + g] = v.x;
        wg[((cl*64) + 4*k4+1)*4 + g] = v.y;
        wg[((cl*64) + 4*k4+2)*4 + g] = v.z;
        wg[((cl*64) + 4*k4+3)*4 + g] = v.w;
    }
    __syncthreads();

    for (int idx = t; idx < 800; idx += 256) {
        const int cl = idx / 50, p = idx - cl * 50;
        const int c  = c_base + cl;
        float s0 = pb2[c], s1 = pb2[256 + c], s2 = pb2[512 + c], s3 = pb2[768 + c];
        const float4* wv = (const float4*)wg + cl * 64;
        #pragma unroll
        for (int k = 0; k < 64; k++) {
            const float x = ht[k*52 + p];      // consecutive lanes -> conflict-free
            const float4 w = wv[k];            // same (cl,k) across lanes -> broadcast
            s0 += x * w.x; s1 += x * w.y; s2 += x * w.z; s3 += x * w.w;
        }
        float mx = fmaxf(fmaxf(s0, s1), fmaxf(s2, s3));
        float e0 = expf(s0-mx), e1 = expf(s1-mx), e2 = expf(s2-mx), e3 = expf(s3-mx);
        float inv = 1.f / (e0+e1+e2+e3);
        e0 *= inv; e1 *= inv; e2 *= inv; e3 *= inv;
        if (p < 49) {
            float wvv = e0*weight1[(0*256+c)*49+p] + e1*weight1[(1*256+c)*49+p]
                      + e2*weight1[(2*256+c)*49+p] + e3*weight1[(3*256+c)*49+p];
            w_dyn[((size_t)b*256 + c)*49 + p] = wvv;   // coalesced along p
        } else {
            b_dyn[b*256 + c] = e0*bias1[c] + e1*bias1[256+c] + e2*bias1[512+c] + e3*bias1[768+c];
        }
    }
}

// ---------------- Kernel 3: recompute x_fuse into LDS halo, then dynamic 7x7 conv ----
// Round-0 version verbatim (44.5 us, VGPR 44, occupancy ~40%).
#define S3 68
__global__ __launch_bounds__(256) void k3_dyn(
    const float* __restrict__ x1,
    const float* __restrict__ dw1w, const float* __restrict__ g1, const float* __restrict__ b1,
    const float* __restrict__ m1, const float* __restrict__ v1,
    const float* __restrict__ dw2w, const float* __restrict__ g2, const float* __restrict__ b2,
    const float* __restrict__ m2, const float* __restrict__ v2,
    const float* __restrict__ w_dyn, const float* __restrict__ b_dyn,
    float* __restrict__ out)
{
    const int bc = blockIdx.x;
    const int c  = bc & 255;
    const int t  = threadIdx.x;
    __shared__ __attribute__((aligned(16))) float halo[62*S3];  // 16.9 KB

    // block-uniform constants (scalar path)
    float w1[9], w2[9];
    #pragma unroll
    for (int k = 0; k < 9; k++) { w1[k] = dw1w[c*9+k]; w2[k] = dw2w[c*9+k]; }
    const float sc1 = g1[c] * rsqrtf(v1[c] + 1e-5f);
    const float be1 = b1[c] - m1[c] * sc1;
    const float sc2 = g2[c] * rsqrtf(v2[c] + 1e-5f);
    const float be2 = b2[c] - m2[c] * sc2;
    float wk[49];
    const float* wp = w_dyn + (size_t)bc * 49;   // block-uniform -> s_loads
    #pragma unroll
    for (int k = 0; k < 49; k++) wk[k] = wp[k];
    const float bias = b_dyn[bc];

    {   // zero halo (borders must be 0; interior overwritten in phase A)
        float4 z = make_float4(0.f, 0.f, 0.f, 0.f);
        float4* h4 = (float4*)halo;
        for (int i = t; i < 62*S3/4; i += 256) h4[i] = z;
    }
    __syncthreads();

    const int ty = t / 14, tx = t - ty * 14;
    if (t < 196) {
        float res[4][4];
        fuse_tile(x1 + (size_t)bc * NPIX, ty, tx, w1, w2, sc1, be1, sc2, be2, res);
        #pragma unroll
        for (int tyy = 0; tyy < 4; tyy++) {
            float4 r4; r4.x=res[tyy][0]; r4.y=res[tyy][1]; r4.z=res[tyy][2]; r4.w=res[tyy][3];
            *(float4*)&halo[(4*ty + tyy + 3)*S3 + 4 + 4*tx] = r4;
        }
    }
    __syncthreads();

    if (t < 196) {
        const int oy = ty * 4, ox = tx * 4;
        float acc[4][4];
        #pragma unroll
        for (int a = 0; a < 4; a++)
            #pragma unroll
            for (int bb = 0; bb < 4; bb++) acc[a][bb] = bias;

        #pragma unroll
        for (int iy = 0; iy < 10; iy++) {
            const float* hr = &halo[(oy+iy)*S3 + ox];  // aligned
            float4 a = *(const float4*)hr;             // 3x ds_read_b128
            float4 b = *(const float4*)(hr + 4);
            float4 cc = *(const float4*)(hr + 8);
            float row[12];                             // row[m] = image col ox+m-4
            row[0]=a.x; row[1]=a.y; row[2]=a.z; row[3]=a.w;
            row[4]=b.x; row[5]=b.y; row[6]=b.z; row[7]=b.w;
            row[8]=cc.x; row[9]=cc.y; row[10]=cc.z; row[11]=cc.w;
            #pragma unroll
            for (int tyy = 0; tyy < 4; tyy++) {
                const int ky = iy - tyy;
                if (ky >= 0 && ky < 7) {
                    #pragma unroll
                    for (int txx = 0; txx < 4; txx++)
                        #pragma unroll
                        for (int kx = 0; kx < 7; kx++)
                            acc[tyy][txx] += row[1+txx+kx] * wk[ky*7+kx];
                }
            }
        }
        float* op = out + (size_t)bc * NPIX;
        #pragma unroll
        for (int tyy = 0; tyy < 4; tyy++) {
            float4 r4; r4.x = acc[tyy][0]; r4.y = acc[tyy][1]; r4.z = acc[tyy][2]; r4.w = acc[tyy][3];
            *(float4*)(op + (oy+tyy)*56 + ox) = r4;
        }
    }
}

extern "C" void kernel_launch(void* const* d_in, const int* in_sizes, int n_in,
                              void* d_out, int out_size, void* d_ws, size_t ws_size,
                              hipStream_t stream) {
    const float* x1    = (const float*)d_in[0];
    const float* dw1w  = (const float*)d_in[1];
    const float* dw1g  = (const float*)d_in[2];
    const float* dw1b  = (const float*)d_in[3];
    const float* dw1m  = (const float*)d_in[4];
    const float* dw1v  = (const float*)d_in[5];
    const float* dw2w  = (const float*)d_in[6];
    const float* dw2g  = (const float*)d_in[7];
    const float* dw2b  = (const float*)d_in[8];
    const float* dw2m  = (const float*)d_in[9];
    const float* dw2v  = (const float*)d_in[10];
    const float* weight1 = (const float*)d_in[11];
    const float* bias1   = (const float*)d_in[12];
    const float* pw1     = (const float*)d_in[13];
    const float* pb1     = (const float*)d_in[14];
    const float* pw2     = (const float*)d_in[15];
    const float* pb2     = (const float*)d_in[16];

    float* out = (float*)d_out;
    float* ws  = (float*)d_ws;
    float* pooled = ws;                    // 16*50*256 = 204,800
    float* h      = ws + 204800;           // 16*50*64  =  51,200
    float* w_dyn  = ws + 256000;           // 16*256*49 = 200,704
    float* b_dyn  = ws + 456704;           // 16*256    =   4,096
    // total ws: 460,800 floats = 1.84 MB (keep small: harness resets d_ws per iter)

    k1_pool<<<BATCH*CH, 256, 0, stream>>>(x1, dw1w, dw1g, dw1b, dw1m, dw1v,
                                          dw2w, dw2g, dw2b, dw2m, dw2v, pooled);
    k2a<<<800, 256, 0, stream>>>(pooled, pw1, pb1, h);
    k2b<<<dim3(BATCH, 16), 256, 0, stream>>>(h, pw2, pb2, weight1, bias1, w_dyn, b_dyn);
    k3_dyn<<<BATCH*CH, 256, 0, stream>>>(x1, dw1w, dw1g, dw1b, dw1m, dw1v,
                                         dw2w, dw2g, dw2b, dw2m, dw2v,
                                         w_dyn, b_dyn, out);
}